// Round 13
// baseline (699.169 us; speedup 1.0000x reference)
//
#include <hip/hip_runtime.h>

// FSU-MGU cell: exact integer reimplementation.
// KEY STRUCTURE (R13): the recurrence is independent across batch rows b —
// gate_h[b,:] needs only h[b,:]. Main loop partitions by b (128 blocks, one
// row each): h lives in LDS, ZERO inter-block communication, one
// __syncthreads per step. h-gate masks stream from L2 in [t][w][j][2] u64
// layout (fully coalesced dwordx4 per thread). x-gates precomputed for all t
// in setup phase D (transposed x-mask region, overwritten in place by xg).

#define NBLK 256
#define NTHR 1024

// workspace layout (bytes); [0,4096) zeroed each call
#define WS_BAR_SUB   0u
#define WS_BAR_MST   1024u
#define WS_BAR_FLG   2048u
#define WS_RNGW   8192u
#define WS_RNGWI  9216u
#define WS_RNGM   10240u
#define WS_SRCB   12288u       // 4096 u16
#define WS_SRCW   20480u       // 4096*1024 u16 (end 8,409,088)
#define WS_XP     8409088u     // 64*128*32 u32 (end 9,457,664)
#define WS_DT     9523200u     // 64*4096 i32 (end 10,571,776)
#define WS_XMASK  10571776u    // 64 slabs x 65536 u64: x-masks [t][w][col<2048]
                               // phase D overwrites each slab with xg[t][b][j]
                               // (131072 u32 = 65536 u64, exact fit). 32 MB.
#define WS_HMASK  44126208u    // 64 slabs x 65536 u64: h-masks [t][w][j][2].
                               // 32 MB. (end 77,680,640 — same as before)

struct SRng {
  unsigned mt[3][624];
  unsigned yb[3][624];
  unsigned draws[3][1248];
  int perm[3][256];
};
struct SC {
  unsigned short rows[16][1028];
  int rngw[64];
  int rngwi[64];
};
struct SD {
  unsigned xst[32*32];                 // staged x rows (broadcast reads)
};
struct SL {
  unsigned h[2][32];                   // h-row bits, double-buffered
  int rngm[16];
};
union SU { SRng r; SC c; SD d; SL l; };

__device__ __forceinline__ unsigned mt_temper(unsigned y){
  y ^= y >> 11;
  y ^= (y << 7)  & 0x9d2c5680u;
  y ^= (y << 15) & 0xefc60000u;
  y ^= y >> 18;
  return y;
}

__device__ void mt_regen_serial(unsigned* mt){
  for (int i = 0; i < 624; i++){
    unsigned y = (mt[i] & 0x80000000u) | (mt[(i+1)%624] & 0x7fffffffu);
    mt[i] = mt[(i+397)%624] ^ (y >> 1) ^ ((y & 1u) ? 0x9908b0dfu : 0u);
  }
}

// numpy legacy RandomState: init_genrand seeding + Fisher-Yates with masked rejection.
__device__ void rng_gen(SU* sm, int* rngw, int* rngwi, int* rngm){
  const int tid = threadIdx.x;
  const int wv = tid >> 6, lane = tid & 63;
  const bool act = (wv < 3);
  if (act && lane == 0){
    unsigned* mt = sm->r.mt[wv];
    mt[0] = (unsigned)wv;  // seeds 0,1,2
    for (int i = 1; i < 624; i++)
      mt[i] = 1812433253u * (mt[i-1] ^ (mt[i-1] >> 30)) + (unsigned)i;
  }
  __syncthreads();
  for (int r = 0; r < 2; r++){
    if (act){
      unsigned* mt = sm->r.mt[wv]; unsigned* yb = sm->r.yb[wv];
      for (int i = lane; i < 623; i += 64)
        yb[i] = (mt[i] & 0x80000000u) | (mt[i+1] & 0x7fffffffu);
    }
    __syncthreads();
    if (act){
      unsigned* mt = sm->r.mt[wv]; unsigned* yb = sm->r.yb[wv];
      for (int i = lane; i < 227; i += 64){
        unsigned y = yb[i];
        mt[i] = mt[i+397] ^ (y >> 1) ^ ((y & 1u) ? 0x9908b0dfu : 0u);
      }
    }
    __syncthreads();
    if (act){
      unsigned* mt = sm->r.mt[wv]; unsigned* yb = sm->r.yb[wv];
      for (int i = 227 + lane; i < 454; i += 64){
        unsigned y = yb[i];
        mt[i] = mt[i-227] ^ (y >> 1) ^ ((y & 1u) ? 0x9908b0dfu : 0u);
      }
    }
    __syncthreads();
    if (act){
      unsigned* mt = sm->r.mt[wv]; unsigned* yb = sm->r.yb[wv];
      for (int i = 454 + lane; i < 624; i += 64){
        unsigned y = (i < 623) ? yb[i]
                   : ((mt[623] & 0x80000000u) | (mt[0] & 0x7fffffffu));
        mt[i] = mt[i-227] ^ (y >> 1) ^ ((y & 1u) ? 0x9908b0dfu : 0u);
      }
    }
    __syncthreads();
    if (act){
      unsigned* mt = sm->r.mt[wv];
      for (int i = lane; i < 624; i += 64)
        sm->r.draws[wv][r*624 + i] = mt_temper(mt[i]);
    }
    __syncthreads();
  }
  if (act && lane == 0){
    const int n = (wv == 2) ? 16 : 256;
    int* perm = sm->r.perm[wv];
    for (int i = 0; i < n; i++) perm[i] = i;
    int dp = 0, spos = 624;
    unsigned* mt = sm->r.mt[wv];
    for (int i = n - 1; i > 0; i--){
      unsigned mask = (unsigned)i;
      mask |= mask >> 1; mask |= mask >> 2; mask |= mask >> 4;
      mask |= mask >> 8; mask |= mask >> 16;
      unsigned v;
      do {
        unsigned d;
        if (dp < 1248) d = sm->r.draws[wv][dp++];
        else {
          if (spos >= 624){ mt_regen_serial(mt); spos = 0; }
          d = mt_temper(mt[spos++]);
        }
        v = d & mask;
      } while (v > (unsigned)i);
      int tmp = perm[i]; perm[i] = perm[v]; perm[v] = tmp;
    }
    int* dst = (wv == 0) ? rngw : (wv == 1) ? rngwi : rngm;
    for (int i = 0; i < n; i++) dst[i] = perm[i];
  }
}

// full-grid barrier WITH fences — publication barriers (setup)
__device__ __forceinline__ void gbar_full(unsigned char* ws, unsigned ep){
  __syncthreads();
  if (threadIdx.x == 0){
    __threadfence();
    unsigned* sub = (unsigned*)(ws + WS_BAR_SUB + (blockIdx.x & 7)*128);
    unsigned old = atomicAdd(sub, 1u);
    if (old == ep*32u - 1u){
      unsigned* mst = (unsigned*)(ws + WS_BAR_MST);
      unsigned mo = atomicAdd(mst, 1u);
      if (mo == ep*8u - 1u){
        for (int i = 0; i < 8; i++)
          __hip_atomic_store((unsigned*)(ws + WS_BAR_FLG + i*128), ep,
                             __ATOMIC_RELAXED, __HIP_MEMORY_SCOPE_AGENT);
      }
    }
    const unsigned* fl = (const unsigned*)(ws + WS_BAR_FLG + (blockIdx.x & 7)*128);
    while (__hip_atomic_load(fl, __ATOMIC_RELAXED, __HIP_MEMORY_SCOPE_AGENT) < ep)
      __builtin_amdgcn_s_sleep(8);
  }
  __syncthreads();
  __threadfence();
}

// full-grid barrier WITHOUT fences — read-completion only (WAR hazards).
__device__ __forceinline__ void gbar_nofence(unsigned char* ws, unsigned ep){
  __syncthreads();
  if (threadIdx.x == 0){
    unsigned* sub = (unsigned*)(ws + WS_BAR_SUB + (blockIdx.x & 7)*128);
    unsigned old = atomicAdd(sub, 1u);
    if (old == ep*32u - 1u){
      unsigned* mst = (unsigned*)(ws + WS_BAR_MST);
      unsigned mo = atomicAdd(mst, 1u);
      if (mo == ep*8u - 1u){
        for (int i = 0; i < 8; i++)
          __hip_atomic_store((unsigned*)(ws + WS_BAR_FLG + i*128), ep,
                             __ATOMIC_RELAXED, __HIP_MEMORY_SCOPE_AGENT);
      }
    }
    const unsigned* fl = (const unsigned*)(ws + WS_BAR_FLG + (blockIdx.x & 7)*128);
    while (__hip_atomic_load(fl, __ATOMIC_RELAXED, __HIP_MEMORY_SCOPE_AGENT) < ep)
      __builtin_amdgcn_s_sleep(8);
  }
  __syncthreads();
}

__device__ __forceinline__ int clampi(int v){
  v = v < -512 ? -512 : v;
  v = v >  512 ?  512 : v;
  return v;
}

// (x & p) | (~x & n)  ->  v_bfi_b32
__device__ __forceinline__ unsigned bfi(unsigned x, unsigned p, unsigned n){
  return (x & p) | (~x & n);
}

__global__ void __launch_bounds__(NTHR, 4)
fsu_kernel(const float* __restrict__ x, const float* __restrict__ hx0,
           const float* __restrict__ wih, const float* __restrict__ bih,
           const float* __restrict__ whh, const float* __restrict__ bhh,
           float* __restrict__ out, unsigned char* __restrict__ ws)
{
  __shared__ SU sm;
  const int tid = threadIdx.x;
  const int bid = blockIdx.x;

  int* rngw  = (int*)(ws + WS_RNGW);
  int* rngwi = (int*)(ws + WS_RNGWI);
  int* rngm  = (int*)(ws + WS_RNGM);
  unsigned short* srcb = (unsigned short*)(ws + WS_SRCB);
  unsigned short* srcw = (unsigned short*)(ws + WS_SRCW);
  unsigned* xp   = (unsigned*)(ws + WS_XP);
  int* Dt = (int*)(ws + WS_DT);
  unsigned long long* xmask = (unsigned long long*)(ws + WS_XMASK);
  unsigned long long* hmask = (unsigned long long*)(ws + WS_HMASK);
  unsigned* xgpool = (unsigned*)(ws + WS_XMASK);   // u32 view; slab 131072 u32

  // ---------- phase 0: RNG tables (block 0) || bit-pack + src build (others)
  if (bid == 0){
    rng_gen(&sm, rngw, rngwi, rngm);
  } else {
    const int gtid = (bid - 1)*NTHR + tid;
    const int lane = tid & 63;
    const int gw = gtid >> 6;
    const int nw = (NBLK-1)*(NTHR/64);
    const int nthr = (NBLK-1)*NTHR;
    for (int ch = gw; ch < 131072; ch += nw){            // x bits
      float v = x[(size_t)ch*64 + lane];
      unsigned long long bal = __ballot(v != 0.0f);
      if ((lane & 31) == 0) xp[ch*2 + (lane >> 5)] = (unsigned)(bal >> lane);
    }
    for (int idx = gtid; idx < 4096*1024; idx += nthr){  // src = round((clip+1)*128)
      int c = idx >> 10, k = idx & 1023;
      float wv2 = (c < 2048) ? wih[(size_t)c*1024 + k] : whh[(size_t)(c - 2048)*1024 + k];
      float cl = fminf(fmaxf(wv2, -1.0f), 1.0f);
      srcw[idx] = (unsigned short)(int)rintf((cl + 1.0f)*0.5f*256.0f);
    }
    for (int c = gtid; c < 4096; c += nthr){
      float bv = (c < 2048) ? bih[c] : bhh[c - 2048];
      float cl = fminf(fmaxf(bv, -1.0f), 1.0f);
      srcb[c] = (unsigned short)(int)rintf((cl + 1.0f)*0.5f*256.0f);
    }
  }
  gbar_full(ws, 1u);

  // ---------- phase C: masks + D' constants (popc(neg) folded in)
  // cols < 2048 (x-gates): x-region, TRANSPOSED [t][w][col] (phase D reads).
  // cols >= 2048 (h-gates): h-region, [t][w][j][2] (main-loop coalesced).
  {
    const int c0 = bid * 16;
    const unsigned* srcw32 = (const unsigned*)srcw;
    for (int q = tid; q < 16*512; q += NTHR){
      int r = q >> 9, w = q & 511;
      ((unsigned*)&sm.c.rows[r][0])[w] = srcw32[(size_t)(c0 + r)*512 + w];
    }
    if (tid < 64) sm.c.rngw[tid] = rngw[tid];
    if (tid >= 64 && tid < 128) sm.c.rngwi[tid - 64] = rngwi[tid - 64];
    __syncthreads();
    const bool xside = (c0 < 2048);
    for (int row = tid; row < 1024; row += NTHR){   // (t, local col)
      int t = row >> 4, lc = row & 15, col = c0 + lc;
      int rp = sm.c.rngw[t], ri = sm.c.rngwi[t];
      int hi = rp > ri ? rp : ri;
      int lo1 = (rp < ri ? rp : ri) + 1;
      bool rihi = (ri >= rp);
      const unsigned* srow = (const unsigned*)&sm.c.rows[lc][0];
      unsigned long long* xsl = xmask + (size_t)t*65536;
      unsigned long long* hsl = hmask + (size_t)t*65536;
      const int g  = (col - 2048) >> 10;      // valid when !xside
      const int jj = (col - 2048) & 1023;
      int cnti = 0, cntn = 0;
      for (int w = 0; w < 32; w++){
        unsigned pos = 0, neg = 0;
        #pragma unroll
        for (int i2 = 15; i2 >= 0; i2--){
          unsigned v2 = srow[w*16 + i2];
          int vH = (int)(v2 >> 16);
          int vL = (int)(v2 & 0xFFFFu);
          pos = (pos << 1) | ((unsigned)(hi - vH) >> 31);   // v > hi
          neg = (neg << 1) | ((unsigned)(vH - lo1) >> 31);  // v <= lo
          pos = (pos << 1) | ((unsigned)(hi - vL) >> 31);
          neg = (neg << 1) | ((unsigned)(vL - lo1) >> 31);
        }
        unsigned long long mval = (unsigned long long)pos
                                | ((unsigned long long)neg << 32);
        if (xside) xsl[(size_t)w*2048 + col] = mval;
        else       hsl[((size_t)w*1024 + jj)*2 + g] = mval;
        cnti += rihi ? __popc(pos) : (32 - __popc(neg));    // count(src > ri)
        cntn += __popc(neg);
      }
      Dt[t*4096 + col] = 1024 - cnti - cntn + (((int)srcb[col] > rp) ? 1 : 0);
    }
  }
  gbar_full(ws, 2u);

  // ---------- phase D: x-gates for all t; coalesced reads, acc[32] in regs.
  // tD = bid & 63: the 4 bq-siblings share an XCD -> x-mask slab L2-local.
  {
    const int tD = bid & 63, bq = bid >> 6;
    {
      int bl = tid >> 5, w = tid & 31;
      sm.d.xst[bl*32 + w] = xp[((size_t)tD*128 + bq*32 + bl)*32 + w];
    }
    __syncthreads();
    const int jcol = tid;
    const int dA = Dt[tD*4096 + jcol] + 2048;          // gate i_f col
    const int dB = Dt[tD*4096 + 1024 + jcol] + 2048;   // gate i_n col
    const unsigned dpack = (unsigned)dA | ((unsigned)dB << 16);
    const unsigned long long* mtb = xmask + (size_t)tD*65536;
    unsigned acc[32];
    #pragma unroll
    for (int b = 0; b < 32; b++) acc[b] = 0;
    for (int w = 0; w < 32; w++){
      unsigned long long a = mtb[(size_t)w*2048 + jcol];         // coalesced
      unsigned long long g = mtb[(size_t)w*2048 + 1024 + jcol];  // coalesced
      unsigned alo = (unsigned)a, ahi = (unsigned)(a >> 32);
      unsigned glo = (unsigned)g, ghi = (unsigned)(g >> 32);
      #pragma unroll
      for (int b = 0; b < 32; b++){
        unsigned xw = sm.d.xst[b*32 + w];   // wave-uniform broadcast
        acc[b] += __popc(bfi(xw, alo, ahi))
                + (__popc(bfi(xw, glo, ghi)) << 16);
      }
    }
    gbar_nofence(ws, 3u);   // WAR only: all x-mask reads done grid-wide
    unsigned* xgst = xgpool + (size_t)tD*131072;
    #pragma unroll
    for (int b = 0; b < 32; b++)
      xgst[(size_t)(bq*32 + b)*1024 + jcol] = acc[b] + dpack;   // coalesced
  }
  gbar_full(ws, 4u);        // publication: xg + h-masks visible everywhere

  // ---------- main recurrence: one block per batch row, fully local
  if (bid >= 128) return;
  const int b = bid;
  const int j = tid;

  if (tid < 16) sm.l.rngm[tid] = rngm[tid];

  int hcur;
  {
    hcur = (hx0[(size_t)b*1024 + j] != 0.0f) ? 1 : 0;
    unsigned long long bal = __ballot(hcur);
    if ((tid & 31) == 0)
      sm.l.h[0][tid >> 5] = (unsigned)(bal >> (tid & 32));
  }
  int A1=0,A2=0,A3=0,A4=0,A5=0,A6=0;
  unsigned sr1=10u, sr2=10u, sr3=10u;
  int i1p=0,i1i=0,i2p=0,i2i=0,i3p=0,i3i=0;
  __syncthreads();

  int cur = 0;
  for (int t = 0; t < 64; t++){
    // per-step constants (coalesced; latency hidden by 16 waves)
    const unsigned xg = xgpool[(size_t)t*131072 + (size_t)b*1024 + j];
    const int dhf = Dt[t*4096 + 2048 + j];
    const int dhn = Dt[t*4096 + 3072 + j];

    // h-gate popc: stream 32 x {hf,hn} mask pairs (dwordx4, coalesced)
    const ulonglong2* mrow = (const ulonglong2*)(hmask + (size_t)t*65536) + j;
    const uint4* hq4 = (const uint4*)sm.l.h[cur];
    int s2 = 0, s3 = 0;
    #pragma unroll
    for (int wq = 0; wq < 8; wq++){
      uint4 hq = hq4[wq];   // broadcast LDS read
      {
        ulonglong2 m = mrow[(size_t)(wq*4 + 0)*1024];
        s2 += __popc(bfi(hq.x, (unsigned)m.x, (unsigned)(m.x >> 32)));
        s3 += __popc(bfi(hq.x, (unsigned)m.y, (unsigned)(m.y >> 32)));
      }
      {
        ulonglong2 m = mrow[(size_t)(wq*4 + 1)*1024];
        s2 += __popc(bfi(hq.y, (unsigned)m.x, (unsigned)(m.x >> 32)));
        s3 += __popc(bfi(hq.y, (unsigned)m.y, (unsigned)(m.y >> 32)));
      }
      {
        ulonglong2 m = mrow[(size_t)(wq*4 + 2)*1024];
        s2 += __popc(bfi(hq.z, (unsigned)m.x, (unsigned)(m.x >> 32)));
        s3 += __popc(bfi(hq.z, (unsigned)m.y, (unsigned)(m.y >> 32)));
      }
      {
        ulonglong2 m = mrow[(size_t)(wq*4 + 3)*1024];
        s2 += __popc(bfi(hq.w, (unsigned)m.x, (unsigned)(m.x >> 32)));
        s3 += __popc(bfi(hq.w, (unsigned)m.y, (unsigned)(m.y >> 32)));
      }
    }
    const int g_hf = dhf + s2;
    const int g_hn = dhn + s3;
    const int xgf = (int)(xg & 0xFFFFu) - 2048;
    const int xgn = (int)(xg >> 16) - 2048;

    // ---- FSU elementwise chain (exact, 2x-scaled ints)
    int s1v = xgf + g_hf;
    A1 = clampi(A1 + 2*s1v - 2049);
    int fg_in = (A1 >= 2); A1 -= fg_in << 1;
    A2 = clampi(A2 + ((fg_in + 1) << 1));
    int fg = (A2 >= 4); A2 -= fg << 2;
    A3 = clampi(A3 + (g_hn << 1) - 1024);
    int hnb = (A3 >= 2); A3 -= hnb << 1;

    sr1 = ((sr1 >> 1) | ((unsigned)hnb << 3)) & 0xFu;
    int ng_prod;
    {
      int cv = __popc(sr1) << 2;
      int bp = cv > sm.l.rngm[i1p & 15];
      int bi = cv > sm.l.rngm[i1i & 15];
      ng_prod = fg ? bp : (1 - bi);
      i1p += fg; i1i += 1 - fg;
    }
    A4 = clampi(A4 + (xgn << 1) - 1024);
    int inb = (A4 >= 2); A4 -= inb << 1;
    A5 = clampi(A5 + ((inb + ng_prod) << 1) - 1);
    int ng = (A5 >= 2); A5 -= ng << 1;

    sr2 = ((sr2 >> 1) | ((unsigned)ng << 3)) & 0xFu;
    int fgi;
    {
      int cv = __popc(sr2) << 2;
      int bp = cv > sm.l.rngm[i2p & 15];
      int bi = cv > sm.l.rngm[i2i & 15];
      fgi = (1 - fg) ? bp : (1 - bi);
      i2p += 1 - fg; i2i += fg;
    }
    sr3 = ((sr3 >> 1) | ((unsigned)hcur << 3)) & 0xFu;
    int fgp;
    {
      int cv = __popc(sr3) << 2;
      int bp = cv > sm.l.rngm[i3p & 15];
      int bi = cv > sm.l.rngm[i3i & 15];
      fgp = fg ? bp : (1 - bi);
      i3p += fg; i3i += 1 - fg;
    }
    A6 = clampi(A6 + ((ng + fgi + fgp) << 1) - 2);
    int hy = (A6 >= 2); A6 -= hy << 1;
    hcur = hy;

    // publish h(t+1) locally (LDS) + output
    {
      unsigned long long bal = __ballot(hy);
      if ((tid & 31) == 0)
        sm.l.h[cur ^ 1][tid >> 5] = (unsigned)(bal >> (tid & 32));
    }
    out[(size_t)t*131072 + (size_t)b*1024 + j] = (float)hy;
    __syncthreads();   // the ONLY per-step synchronization
    cur ^= 1;
  }
}

extern "C" void kernel_launch(void* const* d_in, const int* in_sizes, int n_in,
                              void* d_out, int out_size, void* d_ws, size_t ws_size,
                              hipStream_t stream)
{
  (void)in_sizes; (void)n_in; (void)out_size; (void)ws_size;
  const float* x   = (const float*)d_in[0];
  const float* hx0 = (const float*)d_in[1];
  const float* wih = (const float*)d_in[2];
  const float* bih = (const float*)d_in[3];
  const float* whh = (const float*)d_in[4];
  const float* bhh = (const float*)d_in[5];
  float* out = (float*)d_out;
  unsigned char* ws = (unsigned char*)d_ws;

  hipMemsetAsync(d_ws, 0, 4096, stream);

  void* args[] = { (void*)&x, (void*)&hx0, (void*)&wih, (void*)&bih,
                   (void*)&whh, (void*)&bhh, (void*)&out, (void*)&ws };
  hipLaunchCooperativeKernel(reinterpret_cast<void*>(fsu_kernel),
                             dim3(NBLK), dim3(NTHR), args, 0, stream);
}